// Round 6
// baseline (39755.365 us; speedup 1.0000x reference)
//
#include <hip/hip_runtime.h>
#include <hip/hip_bf16.h>

#define H      1024
#define IN_DIM 512
#define OD     512
#define T_LEN  16384
#define NWG    256    // 4 independent waves per WG; global wave == hidden unit
#define NREP   32     // value-array replicas (contention spreading)
#define RS     (H + 64)        // replica stride in floats (256B pad)
#define PSTRIDE (NREP * RS)    // parity stride in floats

typedef unsigned long long u64;
typedef unsigned int u32;

__device__ __forceinline__ u32 pack_bf(float lo, float hi) {
    u32 a = __float_as_uint(lo); a = (a + 0x7fffu + ((a >> 16) & 1u)) >> 16;          // RNE -> [15:0]
    u32 b = __float_as_uint(hi); b = (b + 0x7fffu + ((b >> 16) & 1u)) & 0xffff0000u;  // RNE -> [31:16]
    return a | b;
}
__device__ __forceinline__ float bf_lo(u32 pk) { return __uint_as_float(pk << 16); }
__device__ __forceinline__ float bf_hi(u32 pk) { return __uint_as_float(pk & 0xffff0000u); }

// 64B LLC-coherent read: 4x dwordx4 with sc0 sc1 (bypass L1/L2, serve from LLC).
// Lap bit and value share a dword -> per-dword HW atomicity makes reads safe.
__device__ __forceinline__ void llc_load64(const u32* p, uint4& a, uint4& b, uint4& c, uint4& d) {
    u64 addr = (u64)p;
    asm volatile(
        "global_load_dwordx4 %0, %4, off sc0 sc1\n\t"
        "global_load_dwordx4 %1, %4, off offset:16 sc0 sc1\n\t"
        "global_load_dwordx4 %2, %4, off offset:32 sc0 sc1\n\t"
        "global_load_dwordx4 %3, %4, off offset:48 sc0 sc1\n\t"
        "s_waitcnt vmcnt(0)"
        : "=&v"(a), "=&v"(b), "=&v"(c), "=&v"(d)
        : "v"(addr)
        : "memory");
}
__device__ __forceinline__ u32 lapdiff(uint4 c, u32 lap) {
    return ((c.x ^ lap) | (c.y ^ lap) | (c.z ^ lap) | (c.w ^ lap)) & 1u;
}

// vals[parity][rep][RS]: f32 h-state, mantissa LSB = lap bit ((tag>>1)&1).
// tag T == h after T steps (h_0 = 0). Consumer iter t reads slot t&1 expecting
// lap (t>>1)&1; producer of tag t+1 writes slot (t+1)&1 with lap ((t+1)>>1)&1.
// Initial: parity0 = 0x00 (h_0 = 0, lap 0 -> valid for t=0), parity1 = 0x01
// bytes (lap 1 -> blocks t=1 until real h_1 arrives).
// Race-freedom: publish(t+1) data-depends (butterfly) on all 64 lanes' lap-
// verified ingest of t; slot overwrite (t+2) needs all tags t+1 -> all waves
// ingested t. Per-lane store ordering: every poll's vmcnt(0) drains prior
// stores, so each replica slot sees strictly initial -> T -> T+2 -> ...
// Each wave is fully independent: no LDS, no __syncthreads in the loop.
__global__ __launch_bounds__(256, 1)
void gru_rec_kernel(const float* __restrict__ X,
                    const float* __restrict__ Wih,
                    const float* __restrict__ Whh,
                    const float* __restrict__ bih,
                    const float* __restrict__ bhh,
                    float* __restrict__ hs,
                    u32* __restrict__ vals)
{
    const int tid  = threadIdx.x;
    const int wave = tid >> 6;
    const int lane = tid & 63;
    const int wg   = blockIdx.x;
    const int gw   = wg * 4 + wave;        // global wave == hidden unit u
    const int u    = gw;

    // ---- weights -> registers, bf16-packed ----
    // h-part: lane l owns h cols [16l, 16l+16); whh_r[g][c] packs (16l+2c, 16l+2c+1)
    u32 whh_r[3][8];
    u32 wih_r[3][4];   // x-part: lane l owns x cols {2l,2l+1}+128c
    #pragma unroll
    for (int g = 0; g < 3; ++g) {
        const float* wr = Whh + (size_t)(g * H + u) * H + 16 * lane;
        #pragma unroll
        for (int c = 0; c < 8; ++c)
            whh_r[g][c] = pack_bf(wr[2 * c], wr[2 * c + 1]);
        const float* wx = Wih + (size_t)(g * H + u) * IN_DIM;
        #pragma unroll
        for (int c = 0; c < 4; ++c)
            wih_r[g][c] = pack_bf(wx[2 * lane + 128 * c], wx[2 * lane + 1 + 128 * c]);
    }
    const float bxr = bih[u], bxz = bih[H + u], bxn = bih[2 * H + u];
    const float bhr = bhh[u], bhz = bhh[H + u], bhn = bhh[2 * H + u];

    // ---- x row for t=0 ----
    float xv[8], xw[8];
    #pragma unroll
    for (int c = 0; c < 4; ++c) {
        float2 v = *(const float2*)(X + 2 * lane + 128 * c);
        xv[2 * c] = v.x; xv[2 * c + 1] = v.y;
    }

    const u32* const mybase = vals + (size_t)(wg & (NREP - 1)) * RS + 16 * lane;
    float hmine = 0.f;   // this wave's own h (== h_t[u]), avoids any extraction

    #pragma unroll 1
    for (int t = 0; t < T_LEN; ++t) {
        // ---- x partials (independent of h; hidden before the spin) ----
        float xr = 0.f, xz = 0.f, xn = 0.f;
        #pragma unroll
        for (int c = 0; c < 4; ++c) {
            const float x0 = xv[2 * c], x1 = xv[2 * c + 1];
            xr += bf_lo(wih_r[0][c]) * x0 + bf_hi(wih_r[0][c]) * x1;
            xz += bf_lo(wih_r[1][c]) * x0 + bf_hi(wih_r[1][c]) * x1;
            xn += bf_lo(wih_r[2][c]) * x0 + bf_hi(wih_r[2][c]) * x1;
        }
        float xns = xn;
        #pragma unroll
        for (int s = 32; s; s >>= 1) xns += __shfl_xor(xns, s, 64);

        // prefetch next x row (in flight during the spin)
        {
            const int tn = (t + 1 < T_LEN) ? (t + 1) : t;
            const float* xp = X + (size_t)tn * IN_DIM;
            #pragma unroll
            for (int c = 0; c < 4; ++c) {
                float2 v = *(const float2*)(xp + 2 * lane + 128 * c);
                xw[2 * c] = v.x; xw[2 * c + 1] = v.y;
            }
        }

        // ---- spin: 64B poll, values self-validate via mantissa-LSB lap ----
        const u32 lapexp = (u32)((t >> 1) & 1);
        const u32* pbase = mybase + (size_t)(t & 1) * PSTRIDE;
        uint4 c0, c1, c2, c3;
        for (;;) {
            llc_load64(pbase, c0, c1, c2, c3);
            if (!(lapdiff(c0, lapexp) | lapdiff(c1, lapexp) |
                  lapdiff(c2, lapexp) | lapdiff(c3, lapexp))) break;
        }

        // rotating coalesced store of PREVIOUS hs row (loaded vals = h_t = hs[t-1])
        if (t && gw == ((t - 1) & (H - 1))) {
            float* dst = hs + (size_t)(t - 1) * H + 16 * lane;
            *(uint4*)(dst + 0)  = c0;
            *(uint4*)(dst + 4)  = c1;
            *(uint4*)(dst + 8)  = c2;
            *(uint4*)(dst + 12) = c3;
        }

        // ---- h partials (values stay lane-local; only sums cross lanes) ----
        float hv[16];
        hv[0]=__uint_as_float(c0.x); hv[1]=__uint_as_float(c0.y); hv[2]=__uint_as_float(c0.z); hv[3]=__uint_as_float(c0.w);
        hv[4]=__uint_as_float(c1.x); hv[5]=__uint_as_float(c1.y); hv[6]=__uint_as_float(c1.z); hv[7]=__uint_as_float(c1.w);
        hv[8]=__uint_as_float(c2.x); hv[9]=__uint_as_float(c2.y); hv[10]=__uint_as_float(c2.z); hv[11]=__uint_as_float(c2.w);
        hv[12]=__uint_as_float(c3.x); hv[13]=__uint_as_float(c3.y); hv[14]=__uint_as_float(c3.z); hv[15]=__uint_as_float(c3.w);

        float ar = xr, az = xz, anh = 0.f;
        #pragma unroll
        for (int c = 0; c < 8; ++c) {
            const float h0 = hv[2 * c], h1 = hv[2 * c + 1];
            ar  += bf_lo(whh_r[0][c]) * h0 + bf_hi(whh_r[0][c]) * h1;
            az  += bf_lo(whh_r[1][c]) * h0 + bf_hi(whh_r[1][c]) * h1;
            anh += bf_lo(whh_r[2][c]) * h0 + bf_hi(whh_r[2][c]) * h1;
        }
        #pragma unroll
        for (int s = 32; s; s >>= 1) {
            ar  += __shfl_xor(ar,  s, 64);
            az  += __shfl_xor(az,  s, 64);
            anh += __shfl_xor(anh, s, 64);
        }

        // ---- gates (all lanes redundantly) + one-instruction 32-replica publish ----
        const float r = 1.f / (1.f + __expf(-(ar + bxr + bhr)));
        const float z = 1.f / (1.f + __expf(-(az + bxz + bhz)));
        const float e2 = __expf(2.f * (xns + bxn + r * (anh + bhn)));
        const float n = 1.f - 2.f / (e2 + 1.f);   // tanh
        const float hnew = (1.f - z) * n + z * hmine;
        const u32 lapw = (u32)(((t + 1) >> 1) & 1);
        const u32 bits = (__float_as_uint(hnew) & ~1u) | lapw;
        hmine = __uint_as_float(bits);
        if (lane < NREP)
            __hip_atomic_store(vals + (size_t)((t + 1) & 1) * PSTRIDE + (size_t)lane * RS + u,
                               bits, __ATOMIC_RELAXED, __HIP_MEMORY_SCOPE_AGENT);
        if (t == T_LEN - 1 && lane == 0)
            hs[(size_t)t * H + u] = hmine;   // final row: tag T_LEN never re-read

        #pragma unroll
        for (int i = 0; i < 8; ++i) xv[i] = xw[i];
    }
}

// out[m,n] = sum_k hs[m,k] * Wfc[n,k] + bfc[n]   (M=16384, N=512, K=1024)
#define BM 64
#define BN 64
#define BK 16
__global__ __launch_bounds__(256)
void fc_kernel(const float* __restrict__ A, const float* __restrict__ B,
               const float* __restrict__ bias, float* __restrict__ C)
{
    __shared__ float As[BK][BM + 4];
    __shared__ float Bs[BK][BN + 4];
    const int tid = threadIdx.x;
    const int m0 = blockIdx.y * BM, n0 = blockIdx.x * BN;
    const int tx = tid & 15, ty = tid >> 4;
    float acc[4][4] = {};
    const int r = tid >> 2, c = (tid & 3) << 2;
    for (int k0 = 0; k0 < H; k0 += BK) {
        float4 va = *(const float4*)(A + (size_t)(m0 + r) * H + (k0 + c));
        As[c + 0][r] = va.x; As[c + 1][r] = va.y; As[c + 2][r] = va.z; As[c + 3][r] = va.w;
        float4 vb = *(const float4*)(B + (size_t)(n0 + r) * H + (k0 + c));
        Bs[c + 0][r] = vb.x; Bs[c + 1][r] = vb.y; Bs[c + 2][r] = vb.z; Bs[c + 3][r] = vb.w;
        __syncthreads();
        #pragma unroll
        for (int kk = 0; kk < BK; ++kk) {
            float4 a4 = *(const float4*)&As[kk][ty * 4];
            float4 b4 = *(const float4*)&Bs[kk][tx * 4];
            const float av[4] = {a4.x, a4.y, a4.z, a4.w};
            const float bv[4] = {b4.x, b4.y, b4.z, b4.w};
            #pragma unroll
            for (int i = 0; i < 4; ++i)
                #pragma unroll
                for (int j = 0; j < 4; ++j)
                    acc[i][j] += av[i] * bv[j];
        }
        __syncthreads();
    }
    #pragma unroll
    for (int i = 0; i < 4; ++i) {
        const int m = m0 + ty * 4 + i;
        #pragma unroll
        for (int j = 0; j < 4; ++j) {
            const int n = n0 + tx * 4 + j;
            C[(size_t)m * OD + n] = acc[i][j] + bias[n];
        }
    }
}

extern "C" void kernel_launch(void* const* d_in, const int* in_sizes, int n_in,
                              void* d_out, int out_size, void* d_ws, size_t ws_size,
                              hipStream_t stream) {
    const float* X   = (const float*)d_in[0];
    const float* Wih = (const float*)d_in[1];
    const float* Whh = (const float*)d_in[2];
    const float* bih = (const float*)d_in[3];
    const float* bhh = (const float*)d_in[4];
    const float* Wfc = (const float*)d_in[5];
    const float* bfc = (const float*)d_in[6];
    float* out = (float*)d_out;

    float* hs  = (float*)d_ws;                                   // 64 MB
    u32*  vals = (u32*)((char*)d_ws + (size_t)T_LEN * H * 4);    // 2*NREP*RS*4 = 278 KB

    // parity0: h_0 = 0.0 with lap 0 (valid for t=0). parity1: lap bit 1
    // (0x01010101 floats) blocks t=1 consumers until the real h_1 arrives.
    hipMemsetAsync(vals, 0x00, (size_t)PSTRIDE * 4, stream);
    hipMemsetAsync(vals + PSTRIDE, 0x01, (size_t)PSTRIDE * 4, stream);

    void* args[] = { (void*)&X, (void*)&Wih, (void*)&Whh, (void*)&bih,
                     (void*)&bhh, (void*)&hs, (void*)&vals };
    hipError_t e = hipLaunchCooperativeKernel((const void*)gru_rec_kernel,
                                              dim3(NWG), dim3(256), args, 0, stream);
    if (e != hipSuccess) {
        gru_rec_kernel<<<dim3(NWG), dim3(256), 0, stream>>>(X, Wih, Whh, bih, bhh, hs, vals);
    }

    dim3 fgrid(OD / BN, T_LEN / BM);
    fc_kernel<<<fgrid, dim3(256), 0, stream>>>(hs, Wfc, bfc, out);
}

// Round 7
// 28595.697 us; speedup vs baseline: 1.3903x; 1.3903x over previous
//
#include <hip/hip_runtime.h>
#include <hip/hip_bf16.h>

#define H      1024
#define IN_DIM 512
#define OD     512
#define T_LEN  16384
#define NWG    256    // 4 independent waves per WG; global wave == hidden unit
#define NREP   16     // value-array replicas (contention/write-amp balance)
#define RS     (H + 64)        // replica stride in floats (256B pad)
#define PSTRIDE (NREP * RS)    // parity stride in floats

typedef unsigned long long u64;
typedef unsigned int u32;

__device__ __forceinline__ u32 pack_bf(float lo, float hi) {
    u32 a = __float_as_uint(lo); a = (a + 0x7fffu + ((a >> 16) & 1u)) >> 16;          // RNE -> [15:0]
    u32 b = __float_as_uint(hi); b = (b + 0x7fffu + ((b >> 16) & 1u)) & 0xffff0000u;  // RNE -> [31:16]
    return a | b;
}
__device__ __forceinline__ float bf_lo(u32 pk) { return __uint_as_float(pk << 16); }
__device__ __forceinline__ float bf_hi(u32 pk) { return __uint_as_float(pk & 0xffff0000u); }

// vals[parity][rep][RS]: f32 h-state, mantissa LSB = lap bit ((tag>>1)&1).
// tag T == h after T steps (h_0 = 0). Consumer iter t reads parity t&1
// expecting lap (t>>1)&1; producer of tag t+1 writes parity (t+1)&1 with lap
// ((t+1)>>1)&1. Lap sequence at a parity slot: 0,1,0,... matches (t>>1)&1.
// Initial: parity0 = 0x00 bytes (h_0 = 0, lap 0 -> valid for t=0);
// parity1 = 0x01 bytes (lap 1 -> blocks t=1 until real h_1 arrives).
// Race-freedom (tag monotonicity): publish(t+1) data-depends (butterfly) on
// all 64 lanes' lap-verified ingest of tag t; overwrite of a parity slot
// (tag t+2) requires its producer to have ingested ALL tag-t+1 values, which
// requires every wave to have published t+1, hence ingested t.
// Coalesced transport: lane l owns h cols {2l,2l+1}+128k (u64 pair per k);
// poll instruction k is 64 lanes x 8B = 512B contiguous -> 8 lines, no
// duplicate line reads within a wave. Loads are u64 RELAXED/AGENT atomics
// (LLC-coherent, the R5-proven path). No LDS, no __syncthreads in the loop.
__global__ __launch_bounds__(256, 1)
void gru_rec_kernel(const float* __restrict__ X,
                    const float* __restrict__ Wih,
                    const float* __restrict__ Whh,
                    const float* __restrict__ bih,
                    const float* __restrict__ bhh,
                    float* __restrict__ hs,
                    u32* __restrict__ vals)
{
    const int tid  = threadIdx.x;
    const int wave = tid >> 6;
    const int lane = tid & 63;
    const int wg   = blockIdx.x;
    const int gw   = wg * 4 + wave;        // global wave == hidden unit u
    const int u    = gw;

    // ---- weights -> registers, bf16-packed; lane l owns cols {2l,2l+1}+128k ----
    u32 whh_r[3][8];   // h-part: k = 0..7
    u32 wih_r[3][4];   // x-part: k = 0..3 (cols {2l,2l+1}+128k)
    #pragma unroll
    for (int g = 0; g < 3; ++g) {
        const float* wr = Whh + (size_t)(g * H + u) * H;
        #pragma unroll
        for (int k = 0; k < 8; ++k)
            whh_r[g][k] = pack_bf(wr[2 * lane + 128 * k], wr[2 * lane + 1 + 128 * k]);
        const float* wx = Wih + (size_t)(g * H + u) * IN_DIM;
        #pragma unroll
        for (int k = 0; k < 4; ++k)
            wih_r[g][k] = pack_bf(wx[2 * lane + 128 * k], wx[2 * lane + 1 + 128 * k]);
    }
    const float bxr = bih[u], bxz = bih[H + u], bxn = bih[2 * H + u];
    const float bhr = bhh[u], bhz = bhh[H + u], bhn = bhh[2 * H + u];

    // ---- x row for t=0 ----
    float xv[8], xw[8];
    #pragma unroll
    for (int k = 0; k < 4; ++k) {
        float2 v = *(const float2*)(X + 2 * lane + 128 * k);
        xv[2 * k] = v.x; xv[2 * k + 1] = v.y;
    }

    const int rep = gw & (NREP - 1);       // my replica (spreads WG's waves too)
    float hmine = 0.f;                     // this wave's own h_t[u], full precision

    #pragma unroll 1
    for (int t = 0; t < T_LEN; ++t) {
        // ---- x partials (independent of h; off the critical path) ----
        float xr = 0.f, xz = 0.f, xn = 0.f;
        #pragma unroll
        for (int k = 0; k < 4; ++k) {
            const float x0 = xv[2 * k], x1 = xv[2 * k + 1];
            xr += bf_lo(wih_r[0][k]) * x0 + bf_hi(wih_r[0][k]) * x1;
            xz += bf_lo(wih_r[1][k]) * x0 + bf_hi(wih_r[1][k]) * x1;
            xn += bf_lo(wih_r[2][k]) * x0 + bf_hi(wih_r[2][k]) * x1;
        }
        float xns = xn;
        #pragma unroll
        for (int s = 32; s; s >>= 1) xns += __shfl_xor(xns, s, 64);

        // prefetch next x row (in flight during the spin)
        {
            const int tn = (t + 1 < T_LEN) ? (t + 1) : t;
            const float* xp = X + (size_t)tn * IN_DIM;
            #pragma unroll
            for (int k = 0; k < 4; ++k) {
                float2 v = *(const float2*)(xp + 2 * lane + 128 * k);
                xw[2 * k] = v.x; xw[2 * k + 1] = v.y;
            }
        }

        // ---- spin: 8 coalesced u64 agent loads; values self-validate via lap ----
        const u32 lapexp = (u32)((t >> 1) & 1);
        const u64* pb = (const u64*)(vals + (size_t)(t & 1) * PSTRIDE
                                          + (size_t)rep * RS) + lane;
        u64 v[8];
        for (;;) {
            #pragma unroll
            for (int k = 0; k < 8; ++k)
                v[k] = __hip_atomic_load(pb + 64 * k, __ATOMIC_RELAXED,
                                         __HIP_MEMORY_SCOPE_AGENT);
            u32 bad = 0;
            #pragma unroll
            for (int k = 0; k < 8; ++k)
                bad |= ((u32)v[k] ^ lapexp) | ((u32)(v[k] >> 32) ^ lapexp);
            if (!(bad & 1u)) break;
        }

        // rotating coalesced store of PREVIOUS hs row (v[] = h_t = reference hs[t-1])
        if (t && gw == ((t - 1) & (H - 1))) {
            u64* dst = (u64*)(hs + (size_t)(t - 1) * H) + lane;
            #pragma unroll
            for (int k = 0; k < 8; ++k) dst[64 * k] = v[k];
        }

        // ---- h partials (lane-local values; only sums cross lanes) ----
        float ar = xr, az = xz, anh = 0.f;
        #pragma unroll
        for (int k = 0; k < 8; ++k) {
            const float h0 = __uint_as_float((u32)v[k]);
            const float h1 = __uint_as_float((u32)(v[k] >> 32));
            ar  += bf_lo(whh_r[0][k]) * h0 + bf_hi(whh_r[0][k]) * h1;
            az  += bf_lo(whh_r[1][k]) * h0 + bf_hi(whh_r[1][k]) * h1;
            anh += bf_lo(whh_r[2][k]) * h0 + bf_hi(whh_r[2][k]) * h1;
        }
        #pragma unroll
        for (int s = 32; s; s >>= 1) {
            ar  += __shfl_xor(ar,  s, 64);
            az  += __shfl_xor(az,  s, 64);
            anh += __shfl_xor(anh, s, 64);
        }

        // ---- gates (all lanes redundantly) + one-instruction NREP publish ----
        const float r = 1.f / (1.f + __expf(-(ar + bxr + bhr)));
        const float z = 1.f / (1.f + __expf(-(az + bxz + bhz)));
        const float e2 = __expf(2.f * (xns + bxn + r * (anh + bhn)));
        const float n = 1.f - 2.f / (e2 + 1.f);   // tanh
        const float hnew = (1.f - z) * n + z * hmine;
        const u32 lapw = (u32)(((t + 1) >> 1) & 1);
        const u32 bits = (__float_as_uint(hnew) & ~1u) | lapw;
        hmine = __uint_as_float(bits);
        if (lane < NREP)
            __hip_atomic_store(vals + (size_t)((t + 1) & 1) * PSTRIDE
                                    + (size_t)lane * RS + u,
                               bits, __ATOMIC_RELAXED, __HIP_MEMORY_SCOPE_AGENT);
        if (t == T_LEN - 1 && lane == 0)
            hs[(size_t)t * H + u] = hmine;   // final row: tag T_LEN never re-read

        #pragma unroll
        for (int i = 0; i < 8; ++i) xv[i] = xw[i];
    }
}

// out[m,n] = sum_k hs[m,k] * Wfc[n,k] + bfc[n]   (M=16384, N=512, K=1024)
#define BM 64
#define BN 64
#define BK 16
__global__ __launch_bounds__(256)
void fc_kernel(const float* __restrict__ A, const float* __restrict__ B,
               const float* __restrict__ bias, float* __restrict__ C)
{
    __shared__ float As[BK][BM + 4];
    __shared__ float Bs[BK][BN + 4];
    const int tid = threadIdx.x;
    const int m0 = blockIdx.y * BM, n0 = blockIdx.x * BN;
    const int tx = tid & 15, ty = tid >> 4;
    float acc[4][4] = {};
    const int r = tid >> 2, c = (tid & 3) << 2;
    for (int k0 = 0; k0 < H; k0 += BK) {
        float4 va = *(const float4*)(A + (size_t)(m0 + r) * H + (k0 + c));
        As[c + 0][r] = va.x; As[c + 1][r] = va.y; As[c + 2][r] = va.z; As[c + 3][r] = va.w;
        float4 vb = *(const float4*)(B + (size_t)(n0 + r) * H + (k0 + c));
        Bs[c + 0][r] = vb.x; Bs[c + 1][r] = vb.y; Bs[c + 2][r] = vb.z; Bs[c + 3][r] = vb.w;
        __syncthreads();
        #pragma unroll
        for (int kk = 0; kk < BK; ++kk) {
            float4 a4 = *(const float4*)&As[kk][ty * 4];
            float4 b4 = *(const float4*)&Bs[kk][tx * 4];
            const float av[4] = {a4.x, a4.y, a4.z, a4.w};
            const float bv[4] = {b4.x, b4.y, b4.z, b4.w};
            #pragma unroll
            for (int i = 0; i < 4; ++i)
                #pragma unroll
                for (int j = 0; j < 4; ++j)
                    acc[i][j] += av[i] * bv[j];
        }
        __syncthreads();
    }
    #pragma unroll
    for (int i = 0; i < 4; ++i) {
        const int m = m0 + ty * 4 + i;
        #pragma unroll
        for (int j = 0; j < 4; ++j) {
            const int n = n0 + tx * 4 + j;
            C[(size_t)m * OD + n] = acc[i][j] + bias[n];
        }
    }
}

extern "C" void kernel_launch(void* const* d_in, const int* in_sizes, int n_in,
                              void* d_out, int out_size, void* d_ws, size_t ws_size,
                              hipStream_t stream) {
    const float* X   = (const float*)d_in[0];
    const float* Wih = (const float*)d_in[1];
    const float* Whh = (const float*)d_in[2];
    const float* bih = (const float*)d_in[3];
    const float* bhh = (const float*)d_in[4];
    const float* Wfc = (const float*)d_in[5];
    const float* bfc = (const float*)d_in[6];
    float* out = (float*)d_out;

    float* hs  = (float*)d_ws;                                   // 64 MB
    u32*  vals = (u32*)((char*)d_ws + (size_t)T_LEN * H * 4);    // 2*PSTRIDE*4 ~ 139 KB

    // parity0: h_0 = 0.0, lap 0 (valid for t=0). parity1: 0x01 bytes -> lap 1
    // blocks t=1 consumers until the real h_1 arrives.
    hipMemsetAsync(vals, 0x00, (size_t)PSTRIDE * 4, stream);
    hipMemsetAsync(vals + PSTRIDE, 0x01, (size_t)PSTRIDE * 4, stream);

    void* args[] = { (void*)&X, (void*)&Wih, (void*)&Whh, (void*)&bih,
                     (void*)&bhh, (void*)&hs, (void*)&vals };
    hipError_t e = hipLaunchCooperativeKernel((const void*)gru_rec_kernel,
                                              dim3(NWG), dim3(256), args, 0, stream);
    if (e != hipSuccess) {
        gru_rec_kernel<<<dim3(NWG), dim3(256), 0, stream>>>(X, Wih, Whh, bih, bhh, hs, vals);
    }

    dim3 fgrid(OD / BN, T_LEN / BM);
    fc_kernel<<<fgrid, dim3(256), 0, stream>>>(hs, Wfc, bfc, out);
}